// Round 1
// baseline (745.346 us; speedup 1.0000x reference)
//
#include <hip/hip_runtime.h>

typedef unsigned int u32;
typedef unsigned short u16;
typedef short s16x8 __attribute__((ext_vector_type(8)));
typedef __bf16 bf16x8 __attribute__((ext_vector_type(8)));
typedef float f32x4 __attribute__((ext_vector_type(4)));

#define KEYMASK 0x7fffffffu
#define IDXCAP 65536

__device__ __forceinline__ u16 f2bf(float f) {
  u32 u = __builtin_bit_cast(u32, f);
  return (u16)((u + 0x7fffu + ((u >> 16) & 1u)) >> 16);
}

// Handles either builtin signature (short8 or __bf16x8) across ROCm versions.
struct ABFrag {
  s16x8 v;
  __device__ operator s16x8() const { return v; }
  __device__ operator bf16x8() const { return __builtin_bit_cast(bf16x8, v); }
};

__device__ __forceinline__ f32x4 mfma_bf16(s16x8 a, s16x8 b, f32x4 c) {
  return __builtin_amdgcn_mfma_f32_16x16x32_bf16(ABFrag{a}, ABFrag{b}, c, 0, 0, 0);
}

__device__ __forceinline__ void async16(void* lds, const void* g) {
  __builtin_amdgcn_global_load_lds(
      (__attribute__((address_space(1))) void*)(const_cast<void*>(g)),
      (__attribute__((address_space(3))) void*)lds, 16, 0, 0);
}

// ---------------- conversion ----------------
__global__ void f32_to_bf16_k(const float4* __restrict__ in, ushort4* __restrict__ out, int n4) {
  int stride = gridDim.x * blockDim.x;
  for (int i = blockIdx.x * blockDim.x + threadIdx.x; i < n4; i += stride) {
    float4 v = in[i];
    ushort4 o;
    o.x = f2bf(v.x); o.y = f2bf(v.y); o.z = f2bf(v.z); o.w = f2bf(v.w);
    out[i] = o;
  }
}

// ---------------- selection (3-pass radix select on |s| bits) ----------------
__global__ void kinit(u32* meta, u32 rank) { meta[0] = rank; }

__global__ void histA_k(const uint4* __restrict__ s, int n4, u32* __restrict__ gh) {
  __shared__ u32 h[1024];
  for (int i = threadIdx.x; i < 1024; i += 256) h[i] = 0;
  __syncthreads();
  int stride = gridDim.x * blockDim.x;
  for (int i = blockIdx.x * blockDim.x + threadIdx.x; i < n4; i += stride) {
    uint4 v = s[i];
    atomicAdd(&h[(v.x & KEYMASK) >> 21], 1u);
    atomicAdd(&h[(v.y & KEYMASK) >> 21], 1u);
    atomicAdd(&h[(v.z & KEYMASK) >> 21], 1u);
    atomicAdd(&h[(v.w & KEYMASK) >> 21], 1u);
  }
  __syncthreads();
  for (int i = threadIdx.x; i < 1024; i += 256) if (h[i]) atomicAdd(&gh[i], h[i]);
}

__global__ void histB_k(const uint4* __restrict__ s, int n4, u32* __restrict__ gh,
                        const u32* __restrict__ meta) {
  u32 selA = meta[1];
  int stride = gridDim.x * blockDim.x;
  for (int i = blockIdx.x * blockDim.x + threadIdx.x; i < n4; i += stride) {
    uint4 v = s[i];
    u32 k;
    k = v.x & KEYMASK; if ((k >> 21) == selA) atomicAdd(&gh[(k >> 6) & 0x7fffu], 1u);
    k = v.y & KEYMASK; if ((k >> 21) == selA) atomicAdd(&gh[(k >> 6) & 0x7fffu], 1u);
    k = v.z & KEYMASK; if ((k >> 21) == selA) atomicAdd(&gh[(k >> 6) & 0x7fffu], 1u);
    k = v.w & KEYMASK; if ((k >> 21) == selA) atomicAdd(&gh[(k >> 6) & 0x7fffu], 1u);
  }
}

__global__ void histC_k(const uint4* __restrict__ s, int n4, u32* __restrict__ gh,
                        const u32* __restrict__ meta) {
  u32 pre = (meta[1] << 15) | meta[2];
  int stride = gridDim.x * blockDim.x;
  for (int i = blockIdx.x * blockDim.x + threadIdx.x; i < n4; i += stride) {
    uint4 v = s[i];
    u32 k;
    k = v.x & KEYMASK; if ((k >> 6) == pre) atomicAdd(&gh[k & 63u], 1u);
    k = v.y & KEYMASK; if ((k >> 6) == pre) atomicAdd(&gh[k & 63u], 1u);
    k = v.z & KEYMASK; if ((k >> 6) == pre) atomicAdd(&gh[k & 63u], 1u);
    k = v.w & KEYMASK; if ((k >> 6) == pre) atomicAdd(&gh[k & 63u], 1u);
  }
}

__global__ void kselect(const u32* __restrict__ hist, int nbins,
                        u32* __restrict__ sel, u32* __restrict__ rank) {
  __shared__ u32 part[256];
  int tid = threadIdx.x;
  int chunk = (nbins + 255) >> 8;
  int start = tid * chunk;
  int end = min(start + chunk, nbins);
  u32 sm = 0;
  for (int i = start; i < end; ++i) sm += hist[i];
  part[tid] = sm;
  __syncthreads();
  if (tid == 0) {
    u32 r = rank[0];
    u32 c = 0; int t = 0;
    for (; t < 256; ++t) { if (c + part[t] > r) break; c += part[t]; }
    u32 rr = r - c;
    int bin = t * chunk;
    for (;;) { u32 hv = hist[bin]; if (rr < hv) break; rr -= hv; ++bin; }
    sel[0] = (u32)bin;
    rank[0] = rr;   // after last stage this is q = #equal-keyed elems to zero
  }
}

// mask+cast fused: wb = (key>=t) ? bf16(w) : 0 ; collect indices where key==t
__global__ void build_wb_k(const float4* __restrict__ w, const uint4* __restrict__ s,
                           ushort4* __restrict__ wb, int n4,
                           u32* __restrict__ meta, u32* __restrict__ idxl) {
  u32 t = (meta[1] << 21) | (meta[2] << 6) | meta[3];
  int stride = gridDim.x * blockDim.x;
  for (int i = blockIdx.x * blockDim.x + threadIdx.x; i < n4; i += stride) {
    uint4 sv = s[i];
    float4 wv = w[i];
    u32 k0 = sv.x & KEYMASK, k1 = sv.y & KEYMASK, k2 = sv.z & KEYMASK, k3 = sv.w & KEYMASK;
    ushort4 o;
    o.x = (k0 >= t) ? f2bf(wv.x) : (u16)0;
    o.y = (k1 >= t) ? f2bf(wv.y) : (u16)0;
    o.z = (k2 >= t) ? f2bf(wv.z) : (u16)0;
    o.w = (k3 >= t) ? f2bf(wv.w) : (u16)0;
    wb[i] = o;
    u32 base = (u32)i * 4u;
    if (k0 == t) { u32 p = atomicAdd(&meta[5], 1u); if (p < IDXCAP) idxl[p] = base; }
    if (k1 == t) { u32 p = atomicAdd(&meta[5], 1u); if (p < IDXCAP) idxl[p] = base + 1u; }
    if (k2 == t) { u32 p = atomicAdd(&meta[5], 1u); if (p < IDXCAP) idxl[p] = base + 2u; }
    if (k3 == t) { u32 p = atomicAdd(&meta[5], 1u); if (p < IDXCAP) idxl[p] = base + 3u; }
  }
}

// stable-argsort tie semantics: zero the q smallest flat indices among equals
__global__ void tiefix_k(u16* __restrict__ wb, const u32* __restrict__ meta,
                         u32* __restrict__ idxl) {
  if (threadIdx.x != 0) return;
  u32 m = meta[5]; if (m > IDXCAP) m = IDXCAP;
  u32 q = meta[0];
  if (q == 0 || m == 0) return;
  for (u32 a = 1; a < m; ++a) {
    u32 v = idxl[a]; int b = (int)a - 1;
    while (b >= 0 && idxl[b] > v) { idxl[b + 1] = idxl[b]; --b; }
    idxl[b + 1] = v;
  }
  if (q > m) q = m;
  for (u32 a = 0; a < q; ++a) wb[idxl[a]] = 0;
}

// ---------------- GEMM: C = A(MxK,bf16) * B(NxK,bf16)^T + bias ----------------
// m97 structure: 128x128 tile, BK=32, 4 waves 2x2, global_load_lds w=16, 2-barrier loop
template <int RELU, int CBF16>
__global__ __launch_bounds__(256) void gemm_bt(
    const u16* __restrict__ A, const u16* __restrict__ B,
    const float* __restrict__ bias, void* __restrict__ Cv,
    int Ntrue, int K) {
  __shared__ __align__(16) u16 As[128 * 32];
  __shared__ __align__(16) u16 Bs[128 * 32];
  const int tid = threadIdx.x;
  const int lane = tid & 63;
  const int wv = tid >> 6;
  const long brow = (long)blockIdx.y * 128;
  const long bcol = (long)blockIdx.x * 128;
  const int wm = (wv >> 1) * 64;
  const int wn = (wv & 1) * 64;

  const u16* gA0 = A + (brow + (tid >> 2)) * (long)K + (tid & 3) * 8;
  const u16* gA1 = gA0 + (size_t)64 * K;
  const u16* gB0 = B + (bcol + (tid >> 2)) * (long)K + (tid & 3) * 8;
  const u16* gB1 = gB0 + (size_t)64 * K;
  char* lA0 = (char*)As + wv * 1024;
  char* lA1 = (char*)As + 4096 + wv * 1024;
  char* lB0 = (char*)Bs + wv * 1024;
  char* lB1 = (char*)Bs + 4096 + wv * 1024;

  f32x4 acc[4][4] = {};
  const int fr = lane & 15;
  const int fk = (lane >> 4) * 8;

  for (int kt = 0; kt < K; kt += 32) {
    async16(lA0, gA0 + kt);
    async16(lA1, gA1 + kt);
    async16(lB0, gB0 + kt);
    async16(lB1, gB1 + kt);
    __syncthreads();  // compiler emits vmcnt(0) drain before barrier
    s16x8 a[4], b[4];
#pragma unroll
    for (int m = 0; m < 4; ++m) a[m] = *(const s16x8*)&As[(wm + m * 16 + fr) * 32 + fk];
#pragma unroll
    for (int n = 0; n < 4; ++n) b[n] = *(const s16x8*)&Bs[(wn + n * 16 + fr) * 32 + fk];
#pragma unroll
    for (int m = 0; m < 4; ++m)
#pragma unroll
      for (int n = 0; n < 4; ++n)
        acc[m][n] = mfma_bf16(a[m], b[n], acc[m][n]);
    __syncthreads();
  }

  // C/D layout (m89-verified): col = lane&15, row = (lane>>4)*4 + i
  const long col0 = bcol + wn + fr;
  const long row0 = brow + wm + ((lane >> 4) << 2);
#pragma unroll
  for (int n = 0; n < 4; ++n) {
    long col = col0 + n * 16;
    if (!CBF16 && col >= Ntrue) continue;
    float bv = bias[col];
#pragma unroll
    for (int m = 0; m < 4; ++m) {
#pragma unroll
      for (int i = 0; i < 4; ++i) {
        float v = acc[m][n][i] + bv;
        if (RELU) v = fmaxf(v, 0.0f);
        long off = (row0 + m * 16 + i) * (long)Ntrue + col;
        if (CBF16) ((u16*)Cv)[off] = f2bf(v);
        else ((float*)Cv)[off] = v;
      }
    }
  }
}

// ---------------- launch ----------------
extern "C" void kernel_launch(void* const* d_in, const int* in_sizes, int n_in,
                              void* d_out, int out_size, void* d_ws, size_t ws_size,
                              hipStream_t stream) {
  const float* x  = (const float*)d_in[0];
  const float* w1 = (const float*)d_in[1];
  const float* s1 = (const float*)d_in[2];
  const float* b1 = (const float*)d_in[3];
  const float* w2 = (const float*)d_in[4];
  const float* s2 = (const float*)d_in[5];
  const float* b2 = (const float*)d_in[6];
  const float* w3 = (const float*)d_in[7];
  const float* s3 = (const float*)d_in[8];
  const float* b3 = (const float*)d_in[9];
  float* out = (float*)d_out;

  char* ws = (char*)d_ws;
  u32* meta  = (u32*)(ws + 0);        // [0]=rank/q [1]=selA [2]=selB [3]=selC [5]=cnt
  u32* histA = (u32*)(ws + 1024);     // 1024 bins
  u32* histC = (u32*)(ws + 5120);     // 64 bins
  u32* histB = (u32*)(ws + 8192);     // 32768 bins -> ends at 139264
  u32* idxl  = (u32*)(ws + 139264);   // 65536 entries
  u16* Wb = (u16*)(ws + (1l << 20));                    // 32 MB (max 4096x4096)
  u16* H1 = (u16*)(ws + (34l << 20));                   // 32 MB
  u16* Xb = (u16*)(ws + (67l << 20));                   // 32 MB, reused as H2
  u16* H2 = Xb;

  // x -> bf16
  f32_to_bf16_k<<<1024, 256, 0, stream>>>((const float4*)x, (ushort4*)Xb, (4096 * 2048) / 4);

  auto select_and_build = [&](const float* w, const float* s, int n) {
    int n4 = n / 4;
    hipMemsetAsync(ws, 0, 139264, stream);
    kinit<<<1, 1, 0, stream>>>(meta, (u32)(n / 2));
    histA_k<<<1024, 256, 0, stream>>>((const uint4*)s, n4, histA);
    kselect<<<1, 256, 0, stream>>>(histA, 1024, meta + 1, meta);
    histB_k<<<1024, 256, 0, stream>>>((const uint4*)s, n4, histB, meta);
    kselect<<<1, 256, 0, stream>>>(histB, 32768, meta + 2, meta);
    histC_k<<<1024, 256, 0, stream>>>((const uint4*)s, n4, histC, meta);
    kselect<<<1, 256, 0, stream>>>(histC, 64, meta + 3, meta);
    build_wb_k<<<1024, 256, 0, stream>>>((const float4*)w, (const uint4*)s,
                                         (ushort4*)Wb, n4, meta, idxl);
    tiefix_k<<<1, 64, 0, stream>>>(Wb, meta, idxl);
  };

  // Layer 1: (4096x2048) -> 4096, relu, bf16 out
  select_and_build(w1, s1, 4096 * 2048);
  gemm_bt<1, 1><<<dim3(32, 32), 256, 0, stream>>>(Xb, Wb, b1, H1, 4096, 2048);

  // Layer 2: 4096 -> 4096, relu, bf16 out (H2 overwrites Xb region; Xb is dead)
  select_and_build(w2, s2, 4096 * 4096);
  gemm_bt<1, 1><<<dim3(32, 32), 256, 0, stream>>>(H1, Wb, b2, H2, 4096, 4096);

  // Layer 3: 4096 -> 1000 (padded to 1024), fp32 out + bias, no relu
  select_and_build(w3, s3, 1000 * 4096);
  hipMemsetAsync((char*)Wb + (size_t)1000 * 4096 * 2, 0, (size_t)24 * 4096 * 2, stream);
  gemm_bt<0, 0><<<dim3(8, 32), 256, 0, stream>>>(H2, Wb, b3, out, 1000, 4096);
}

// Round 2
// 651.473 us; speedup vs baseline: 1.1441x; 1.1441x over previous
//
#include <hip/hip_runtime.h>

typedef unsigned int u32;
typedef unsigned short u16;
typedef short s16x8 __attribute__((ext_vector_type(8)));
typedef __bf16 bf16x8 __attribute__((ext_vector_type(8)));
typedef float f32x4 __attribute__((ext_vector_type(4)));

#define KEYMASK 0x7fffffffu
#define IDXCAP 65536

__device__ __forceinline__ u16 f2bf(float f) {
  u32 u = __builtin_bit_cast(u32, f);
  return (u16)((u + 0x7fffu + ((u >> 16) & 1u)) >> 16);
}

// Handles either builtin signature (short8 or __bf16x8) across ROCm versions.
struct ABFrag {
  s16x8 v;
  __device__ operator s16x8() const { return v; }
  __device__ operator bf16x8() const { return __builtin_bit_cast(bf16x8, v); }
};

__device__ __forceinline__ f32x4 mfma_bf16(s16x8 a, s16x8 b, f32x4 c) {
  return __builtin_amdgcn_mfma_f32_16x16x32_bf16(ABFrag{a}, ABFrag{b}, c, 0, 0, 0);
}

__device__ __forceinline__ void async16(void* lds, const void* g) {
  __builtin_amdgcn_global_load_lds(
      (__attribute__((address_space(1))) void*)(const_cast<void*>(g)),
      (__attribute__((address_space(3))) void*)lds, 16, 0, 0);
}

// ---------------- conversion ----------------
__global__ void f32_to_bf16_k(const float4* __restrict__ in, ushort4* __restrict__ out, int n4) {
  int stride = gridDim.x * blockDim.x;
  for (int i = blockIdx.x * blockDim.x + threadIdx.x; i < n4; i += stride) {
    float4 v = in[i];
    ushort4 o;
    o.x = f2bf(v.x); o.y = f2bf(v.y); o.z = f2bf(v.z); o.w = f2bf(v.w);
    out[i] = o;
  }
}

// ---------------- selection (3-pass radix select on |s| bits) ----------------
__global__ void kinit(u32* meta, u32 rank) { meta[0] = rank; }

__global__ void histA_k(const uint4* __restrict__ s, int n4, u32* __restrict__ gh) {
  __shared__ u32 h[1024];
  for (int i = threadIdx.x; i < 1024; i += 256) h[i] = 0;
  __syncthreads();
  int stride = gridDim.x * blockDim.x;
  for (int i = blockIdx.x * blockDim.x + threadIdx.x; i < n4; i += stride) {
    uint4 v = s[i];
    atomicAdd(&h[(v.x & KEYMASK) >> 21], 1u);
    atomicAdd(&h[(v.y & KEYMASK) >> 21], 1u);
    atomicAdd(&h[(v.z & KEYMASK) >> 21], 1u);
    atomicAdd(&h[(v.w & KEYMASK) >> 21], 1u);
  }
  __syncthreads();
  for (int i = threadIdx.x; i < 1024; i += 256) if (h[i]) atomicAdd(&gh[i], h[i]);
}

__global__ void histB_k(const uint4* __restrict__ s, int n4, u32* __restrict__ gh,
                        const u32* __restrict__ meta) {
  u32 selA = meta[1];
  int stride = gridDim.x * blockDim.x;
  for (int i = blockIdx.x * blockDim.x + threadIdx.x; i < n4; i += stride) {
    uint4 v = s[i];
    u32 k;
    k = v.x & KEYMASK; if ((k >> 21) == selA) atomicAdd(&gh[(k >> 6) & 0x7fffu], 1u);
    k = v.y & KEYMASK; if ((k >> 21) == selA) atomicAdd(&gh[(k >> 6) & 0x7fffu], 1u);
    k = v.z & KEYMASK; if ((k >> 21) == selA) atomicAdd(&gh[(k >> 6) & 0x7fffu], 1u);
    k = v.w & KEYMASK; if ((k >> 21) == selA) atomicAdd(&gh[(k >> 6) & 0x7fffu], 1u);
  }
}

__global__ void histC_k(const uint4* __restrict__ s, int n4, u32* __restrict__ gh,
                        const u32* __restrict__ meta) {
  u32 pre = (meta[1] << 15) | meta[2];
  int stride = gridDim.x * blockDim.x;
  for (int i = blockIdx.x * blockDim.x + threadIdx.x; i < n4; i += stride) {
    uint4 v = s[i];
    u32 k;
    k = v.x & KEYMASK; if ((k >> 6) == pre) atomicAdd(&gh[k & 63u], 1u);
    k = v.y & KEYMASK; if ((k >> 6) == pre) atomicAdd(&gh[k & 63u], 1u);
    k = v.z & KEYMASK; if ((k >> 6) == pre) atomicAdd(&gh[k & 63u], 1u);
    k = v.w & KEYMASK; if ((k >> 6) == pre) atomicAdd(&gh[k & 63u], 1u);
  }
}

__global__ void kselect(const u32* __restrict__ hist, int nbins,
                        u32* __restrict__ sel, u32* __restrict__ rank) {
  __shared__ u32 part[256];
  int tid = threadIdx.x;
  int chunk = (nbins + 255) >> 8;
  int start = tid * chunk;
  int end = min(start + chunk, nbins);
  u32 sm = 0;
  for (int i = start; i < end; ++i) sm += hist[i];
  part[tid] = sm;
  __syncthreads();
  if (tid == 0) {
    u32 r = rank[0];
    u32 c = 0; int t = 0;
    for (; t < 256; ++t) { if (c + part[t] > r) break; c += part[t]; }
    u32 rr = r - c;
    int bin = t * chunk;
    for (;;) { u32 hv = hist[bin]; if (rr < hv) break; rr -= hv; ++bin; }
    sel[0] = (u32)bin;
    rank[0] = rr;   // after last stage this is q = #equal-keyed elems to zero
  }
}

// mask+cast fused: wb = (key>=t) ? bf16(w) : 0 ; collect indices where key==t
__global__ void build_wb_k(const float4* __restrict__ w, const uint4* __restrict__ s,
                           ushort4* __restrict__ wb, int n4,
                           u32* __restrict__ meta, u32* __restrict__ idxl) {
  u32 t = (meta[1] << 21) | (meta[2] << 6) | meta[3];
  int stride = gridDim.x * blockDim.x;
  for (int i = blockIdx.x * blockDim.x + threadIdx.x; i < n4; i += stride) {
    uint4 sv = s[i];
    float4 wv = w[i];
    u32 k0 = sv.x & KEYMASK, k1 = sv.y & KEYMASK, k2 = sv.z & KEYMASK, k3 = sv.w & KEYMASK;
    ushort4 o;
    o.x = (k0 >= t) ? f2bf(wv.x) : (u16)0;
    o.y = (k1 >= t) ? f2bf(wv.y) : (u16)0;
    o.z = (k2 >= t) ? f2bf(wv.z) : (u16)0;
    o.w = (k3 >= t) ? f2bf(wv.w) : (u16)0;
    wb[i] = o;
    u32 base = (u32)i * 4u;
    if (k0 == t) { u32 p = atomicAdd(&meta[5], 1u); if (p < IDXCAP) idxl[p] = base; }
    if (k1 == t) { u32 p = atomicAdd(&meta[5], 1u); if (p < IDXCAP) idxl[p] = base + 1u; }
    if (k2 == t) { u32 p = atomicAdd(&meta[5], 1u); if (p < IDXCAP) idxl[p] = base + 2u; }
    if (k3 == t) { u32 p = atomicAdd(&meta[5], 1u); if (p < IDXCAP) idxl[p] = base + 3u; }
  }
}

// stable-argsort tie semantics: zero the q smallest flat indices among equals
__global__ void tiefix_k(u16* __restrict__ wb, const u32* __restrict__ meta,
                         u32* __restrict__ idxl) {
  if (threadIdx.x != 0) return;
  u32 m = meta[5]; if (m > IDXCAP) m = IDXCAP;
  u32 q = meta[0];
  if (q == 0 || m == 0) return;
  for (u32 a = 1; a < m; ++a) {
    u32 v = idxl[a]; int b = (int)a - 1;
    while (b >= 0 && idxl[b] > v) { idxl[b + 1] = idxl[b]; --b; }
    idxl[b + 1] = v;
  }
  if (q > m) q = m;
  for (u32 a = 0; a < q; ++a) wb[idxl[a]] = 0;
}

// ============ 256x256 tile GEMM, BK=64, 8 waves, counted-vmcnt pipeline ============
// C(MxN,bf16) = relu(A(MxK,bf16) * B(NxK,bf16)^T + bias). M,N multiples of 256, K of 64.
// LDS: 2 dbuf x (A 256x64 + B 256x64) bf16 = 128 KiB. T2 swizzle: 16B granule of
// row r lives at granule g^(r&7) (inverse-swizzled global source, swizzled ds_read).
__global__ __launch_bounds__(512, 2) void gemm256(
    const u16* __restrict__ A, const u16* __restrict__ B,
    const float* __restrict__ bias, u16* __restrict__ C,
    int N, int K) {
  __shared__ __align__(16) u16 As[2][256 * 64];
  __shared__ __align__(16) u16 Bs[2][256 * 64];
  const int tid = threadIdx.x;
  const int lane = tid & 63;
  const int wv = tid >> 6;       // 0..7
  const int wm = wv >> 2;        // 0..1  (wave row: 128 output rows)
  const int wn = wv & 3;         // 0..3  (wave col: 64 output cols)
  const int fr = lane & 15;
  const int fkg = lane >> 4;     // 0..3
  const long brow = (long)blockIdx.y * 256;
  const long bcol = (long)blockIdx.x * 256;

  // ---- staging pointers (per thread): row = j*64 + tid>>3, granule (tid&7)^(row&7)
  const int srow = tid >> 3;
  const int sgran = (tid & 7) ^ (srow & 7);
  const u16* pA[4];
  const u16* pB[4];
#pragma unroll
  for (int j = 0; j < 4; ++j) {
    pA[j] = A + (size_t)(brow + j * 64 + srow) * (size_t)K + sgran * 8;
    pB[j] = B + (size_t)(bcol + j * 64 + srow) * (size_t)K + sgran * 8;
  }
  char* lA[2]; char* lB[2];
  lA[0] = (char*)&As[0][0] + wv * 1024;
  lA[1] = (char*)&As[1][0] + wv * 1024;
  lB[0] = (char*)&Bs[0][0] + wv * 1024;
  lB[1] = (char*)&Bs[1][0] + wv * 1024;

  const int NT = K >> 6;

  // prologue: stage K-tiles 0 and 1 (16 loads in flight)
#pragma unroll
  for (int j = 0; j < 4; ++j) { async16(lA[0] + j * 8192, pA[j]); async16(lB[0] + j * 8192, pB[j]); }
#pragma unroll
  for (int j = 0; j < 4; ++j) { async16(lA[1] + j * 8192, pA[j] + 64); async16(lB[1] + j * 8192, pB[j] + 64); }

  f32x4 acc[8][4] = {};
  const int kswz = (fr & 7) << 4;  // byte swizzle, row&7 == fr&7 for all fragment rows

  for (int t = 0; t < NT; ++t) {
    // counted wait: tile t landed; tile t+1 (8 loads) stays in flight
    if (t < NT - 1) { asm volatile("s_waitcnt vmcnt(8)" ::: "memory"); }
    else           { asm volatile("s_waitcnt vmcnt(0)" ::: "memory"); }
    __builtin_amdgcn_sched_barrier(0);
    __builtin_amdgcn_s_barrier();
    __builtin_amdgcn_sched_barrier(0);

    const char* Ab = (const char*)&As[t & 1][0];
    const char* Bb = (const char*)&Bs[t & 1][0];
#pragma unroll
    for (int ks = 0; ks < 2; ++ks) {
      const int ko = (ks * 64 + fkg * 16) ^ kswz;   // swizzled byte col
      s16x8 a[8], b[4];
#pragma unroll
      for (int mf = 0; mf < 8; ++mf)
        a[mf] = *(const s16x8*)(Ab + (wm * 128 + mf * 16 + fr) * 128 + ko);
#pragma unroll
      for (int nf = 0; nf < 4; ++nf)
        b[nf] = *(const s16x8*)(Bb + (wn * 64 + nf * 16 + fr) * 128 + ko);
      __builtin_amdgcn_s_setprio(1);
#pragma unroll
      for (int mf = 0; mf < 8; ++mf)
#pragma unroll
        for (int nf = 0; nf < 4; ++nf)
          acc[mf][nf] = mfma_bf16(a[mf], b[nf], acc[mf][nf]);
      __builtin_amdgcn_s_setprio(0);
    }

    __builtin_amdgcn_sched_barrier(0);
    __builtin_amdgcn_s_barrier();   // all waves done reading buf[t&1]
    __builtin_amdgcn_sched_barrier(0);

    if (t + 2 < NT) {   // stage tile t+2 into the just-freed buffer
      const int kt = (t + 2) << 6;
      char* dA = lA[t & 1]; char* dB = lB[t & 1];
#pragma unroll
      for (int j = 0; j < 4; ++j) { async16(dA + j * 8192, pA[j] + kt); async16(dB + j * 8192, pB[j] + kt); }
    }
  }

  // epilogue: C/D layout col=lane&15, row=(lane>>4)*4+i (m89-verified)
#pragma unroll
  for (int nf = 0; nf < 4; ++nf) {
    const long col = bcol + wn * 64 + nf * 16 + fr;
    const float bv = bias[col];
#pragma unroll
    for (int mf = 0; mf < 8; ++mf) {
      const long row0 = brow + wm * 128 + mf * 16 + fkg * 4;
#pragma unroll
      for (int i = 0; i < 4; ++i) {
        float v = fmaxf(acc[mf][nf][i] + bv, 0.0f);
        C[(row0 + i) * (long)N + col] = f2bf(v);
      }
    }
  }
}

// ---------------- 128x128 GEMM (kept for layer 3: N=1024 needs 256 blocks) ----------------
template <int RELU, int CBF16>
__global__ __launch_bounds__(256) void gemm_bt(
    const u16* __restrict__ A, const u16* __restrict__ B,
    const float* __restrict__ bias, void* __restrict__ Cv,
    int Ntrue, int K) {
  __shared__ __align__(16) u16 As[128 * 32];
  __shared__ __align__(16) u16 Bs[128 * 32];
  const int tid = threadIdx.x;
  const int lane = tid & 63;
  const int wv = tid >> 6;
  const long brow = (long)blockIdx.y * 128;
  const long bcol = (long)blockIdx.x * 128;
  const int wm = (wv >> 1) * 64;
  const int wn = (wv & 1) * 64;

  const u16* gA0 = A + (brow + (tid >> 2)) * (long)K + (tid & 3) * 8;
  const u16* gA1 = gA0 + (size_t)64 * K;
  const u16* gB0 = B + (bcol + (tid >> 2)) * (long)K + (tid & 3) * 8;
  const u16* gB1 = gB0 + (size_t)64 * K;
  char* lA0 = (char*)As + wv * 1024;
  char* lA1 = (char*)As + 4096 + wv * 1024;
  char* lB0 = (char*)Bs + wv * 1024;
  char* lB1 = (char*)Bs + 4096 + wv * 1024;

  f32x4 acc[4][4] = {};
  const int fr = lane & 15;
  const int fk = (lane >> 4) * 8;

  for (int kt = 0; kt < K; kt += 32) {
    async16(lA0, gA0 + kt);
    async16(lA1, gA1 + kt);
    async16(lB0, gB0 + kt);
    async16(lB1, gB1 + kt);
    __syncthreads();
    s16x8 a[4], b[4];
#pragma unroll
    for (int m = 0; m < 4; ++m) a[m] = *(const s16x8*)&As[(wm + m * 16 + fr) * 32 + fk];
#pragma unroll
    for (int n = 0; n < 4; ++n) b[n] = *(const s16x8*)&Bs[(wn + n * 16 + fr) * 32 + fk];
#pragma unroll
    for (int m = 0; m < 4; ++m)
#pragma unroll
      for (int n = 0; n < 4; ++n)
        acc[m][n] = mfma_bf16(a[m], b[n], acc[m][n]);
    __syncthreads();
  }

  const long col0 = bcol + wn + fr;
  const long row0 = brow + wm + ((lane >> 4) << 2);
#pragma unroll
  for (int n = 0; n < 4; ++n) {
    long col = col0 + n * 16;
    if (!CBF16 && col >= Ntrue) continue;
    float bv = bias[col];
#pragma unroll
    for (int m = 0; m < 4; ++m) {
#pragma unroll
      for (int i = 0; i < 4; ++i) {
        float v = acc[m][n][i] + bv;
        if (RELU) v = fmaxf(v, 0.0f);
        long off = (row0 + m * 16 + i) * (long)Ntrue + col;
        if (CBF16) ((u16*)Cv)[off] = f2bf(v);
        else ((float*)Cv)[off] = v;
      }
    }
  }
}

// ---------------- launch ----------------
extern "C" void kernel_launch(void* const* d_in, const int* in_sizes, int n_in,
                              void* d_out, int out_size, void* d_ws, size_t ws_size,
                              hipStream_t stream) {
  const float* x  = (const float*)d_in[0];
  const float* w1 = (const float*)d_in[1];
  const float* s1 = (const float*)d_in[2];
  const float* b1 = (const float*)d_in[3];
  const float* w2 = (const float*)d_in[4];
  const float* s2 = (const float*)d_in[5];
  const float* b2 = (const float*)d_in[6];
  const float* w3 = (const float*)d_in[7];
  const float* s3 = (const float*)d_in[8];
  const float* b3 = (const float*)d_in[9];
  float* out = (float*)d_out;

  char* ws = (char*)d_ws;
  u32* meta  = (u32*)(ws + 0);        // [0]=rank/q [1]=selA [2]=selB [3]=selC [5]=cnt
  u32* histA = (u32*)(ws + 1024);     // 1024 bins
  u32* histC = (u32*)(ws + 5120);     // 64 bins
  u32* histB = (u32*)(ws + 8192);     // 32768 bins -> ends at 139264
  u32* idxl  = (u32*)(ws + 139264);   // 65536 entries
  u16* Wb = (u16*)(ws + (1l << 20));                    // 32 MB (max 4096x4096)
  u16* H1 = (u16*)(ws + (34l << 20));                   // 32 MB
  u16* Xb = (u16*)(ws + (67l << 20));                   // 32 MB, reused as H2
  u16* H2 = Xb;

  // x -> bf16
  f32_to_bf16_k<<<1024, 256, 0, stream>>>((const float4*)x, (ushort4*)Xb, (4096 * 2048) / 4);

  auto select_and_build = [&](const float* w, const float* s, int n) {
    int n4 = n / 4;
    hipMemsetAsync(ws, 0, 139264, stream);
    kinit<<<1, 1, 0, stream>>>(meta, (u32)(n / 2));
    histA_k<<<1024, 256, 0, stream>>>((const uint4*)s, n4, histA);
    kselect<<<1, 256, 0, stream>>>(histA, 1024, meta + 1, meta);
    histB_k<<<1024, 256, 0, stream>>>((const uint4*)s, n4, histB, meta);
    kselect<<<1, 256, 0, stream>>>(histB, 32768, meta + 2, meta);
    histC_k<<<1024, 256, 0, stream>>>((const uint4*)s, n4, histC, meta);
    kselect<<<1, 256, 0, stream>>>(histC, 64, meta + 3, meta);
    build_wb_k<<<1024, 256, 0, stream>>>((const float4*)w, (const uint4*)s,
                                         (ushort4*)Wb, n4, meta, idxl);
    tiefix_k<<<1, 64, 0, stream>>>(Wb, meta, idxl);
  };

  // Layer 1: (4096x2048) -> 4096, relu, bf16 out
  select_and_build(w1, s1, 4096 * 2048);
  gemm256<<<dim3(16, 16), 512, 0, stream>>>(Xb, Wb, b1, H1, 4096, 2048);

  // Layer 2: 4096 -> 4096, relu, bf16 out (H2 overwrites Xb region; Xb is dead)
  select_and_build(w2, s2, 4096 * 4096);
  gemm256<<<dim3(16, 16), 512, 0, stream>>>(H1, Wb, b2, H2, 4096, 4096);

  // Layer 3: 4096 -> 1000 (padded to 1024), fp32 out + bias, no relu
  select_and_build(w3, s3, 1000 * 4096);
  hipMemsetAsync((char*)Wb + (size_t)1000 * 4096 * 2, 0, (size_t)24 * 4096 * 2, stream);
  gemm_bt<0, 0><<<dim3(8, 32), 256, 0, stream>>>(H2, Wb, b3, out, 1000, 4096);
}

// Round 3
// 490.993 us; speedup vs baseline: 1.5180x; 1.3268x over previous
//
#include <hip/hip_runtime.h>

typedef unsigned int u32;
typedef unsigned short u16;
typedef short s16x8 __attribute__((ext_vector_type(8)));
typedef __bf16 bf16x8 __attribute__((ext_vector_type(8)));
typedef float f32x4 __attribute__((ext_vector_type(4)));

#define KEYMASK 0x7fffffffu
#define NB1 1024
#define NB2 4096
#define CANDCAP 65536
#define TIECAP 2048

__device__ __forceinline__ u16 f2bf(float f) {
  u32 u = __builtin_bit_cast(u32, f);
  return (u16)((u + 0x7fffu + ((u >> 16) & 1u)) >> 16);
}

// Handles either builtin signature (short8 or __bf16x8) across ROCm versions.
struct ABFrag {
  s16x8 v;
  __device__ operator s16x8() const { return v; }
  __device__ operator bf16x8() const { return __builtin_bit_cast(bf16x8, v); }
};

__device__ __forceinline__ f32x4 mfma_bf16(s16x8 a, s16x8 b, f32x4 c) {
  return __builtin_amdgcn_mfma_f32_16x16x32_bf16(ABFrag{a}, ABFrag{b}, c, 0, 0, 0);
}

__device__ __forceinline__ void async16(void* lds, const void* g) {
  __builtin_amdgcn_global_load_lds(
      (__attribute__((address_space(1))) void*)(const_cast<void*>(g)),
      (__attribute__((address_space(3))) void*)lds, 16, 0, 0);
}

// ---------------- conversion ----------------
__global__ void f32_to_bf16_k(const float4* __restrict__ in, ushort4* __restrict__ out, int n4) {
  int stride = gridDim.x * blockDim.x;
  for (int i = blockIdx.x * blockDim.x + threadIdx.x; i < n4; i += stride) {
    float4 v = in[i];
    ushort4 o;
    o.x = f2bf(v.x); o.y = f2bf(v.y); o.z = f2bf(v.z); o.w = f2bf(v.w);
    out[i] = o;
  }
}

// ================= fused 3-layer radix selection =================
// meta layout per layer (8 u32): [0]=selA(10b) [1]=r1 [2]=selB(12b) [3]=r2 [4]=candCount

// Pass 1: 10-bit prefix histogram (key>>21), all 3 layers, 4-way replicated bins
// (|uniform| mass concentrates in ~4 top-octave bins -> replicate to cut LDS
// same-address atomic serialization).
__global__ void hist1_k(const uint4* __restrict__ sa, int na,
                        const uint4* __restrict__ sb, int nb,
                        const uint4* __restrict__ sc, int nc,
                        u32* __restrict__ gh) {
  __shared__ u32 h[3 * NB1 * 4];  // 48KB: [l][bin][replica]
  for (int i = threadIdx.x; i < 3 * NB1 * 4; i += blockDim.x) h[i] = 0;
  __syncthreads();
  const int rep = threadIdx.x & 3;
  const uint4* sp[3] = {sa, sb, sc};
  int nn[3] = {na, nb, nc};
  int stride = gridDim.x * blockDim.x;
  for (int l = 0; l < 3; ++l) {
    const uint4* s = sp[l];
    int n4 = nn[l];
    u32* hl = &h[l * NB1 * 4 + rep];
    for (int i = blockIdx.x * blockDim.x + threadIdx.x; i < n4; i += stride) {
      uint4 v = s[i];
      atomicAdd(&hl[((v.x & KEYMASK) >> 21) * 4], 1u);
      atomicAdd(&hl[((v.y & KEYMASK) >> 21) * 4], 1u);
      atomicAdd(&hl[((v.z & KEYMASK) >> 21) * 4], 1u);
      atomicAdd(&hl[((v.w & KEYMASK) >> 21) * 4], 1u);
    }
  }
  __syncthreads();
  for (int i = threadIdx.x; i < 3 * NB1; i += blockDim.x) {
    u32 c = h[i * 4] + h[i * 4 + 1] + h[i * 4 + 2] + h[i * 4 + 3];
    if (c) atomicAdd(&gh[i], c);
  }
}

// Pass 2: 12-bit sub-histogram (bits 20..9) of elements whose 10-bit prefix == selA.
__global__ void hist2_k(const uint4* __restrict__ sa, int na,
                        const uint4* __restrict__ sb, int nb,
                        const uint4* __restrict__ sc, int nc,
                        u32* __restrict__ gh, const u32* __restrict__ meta) {
  __shared__ u32 h[3 * NB2];  // 48KB
  for (int i = threadIdx.x; i < 3 * NB2; i += blockDim.x) h[i] = 0;
  __syncthreads();
  const uint4* sp[3] = {sa, sb, sc};
  int nn[3] = {na, nb, nc};
  int stride = gridDim.x * blockDim.x;
  for (int l = 0; l < 3; ++l) {
    const uint4* s = sp[l];
    int n4 = nn[l];
    u32 selA = meta[l * 8 + 0];
    u32* hl = &h[l * NB2];
    for (int i = blockIdx.x * blockDim.x + threadIdx.x; i < n4; i += stride) {
      uint4 v = s[i];
      u32 k;
      k = v.x & KEYMASK; if ((k >> 21) == selA) atomicAdd(&hl[(k >> 9) & 0xfffu], 1u);
      k = v.y & KEYMASK; if ((k >> 21) == selA) atomicAdd(&hl[(k >> 9) & 0xfffu], 1u);
      k = v.z & KEYMASK; if ((k >> 21) == selA) atomicAdd(&hl[(k >> 9) & 0xfffu], 1u);
      k = v.w & KEYMASK; if ((k >> 21) == selA) atomicAdd(&hl[(k >> 9) & 0xfffu], 1u);
    }
  }
  __syncthreads();
  for (int i = threadIdx.x; i < 3 * NB2; i += blockDim.x) {
    u32 c = h[i];
    if (c) atomicAdd(&gh[i], c);
  }
}

// One block per layer: walk the histogram to the rank'th element.
template <int STAGE>
__global__ void select_k(const u32* __restrict__ hist, u32* __restrict__ meta,
                         u32 r0, u32 r1, u32 r2) {
  const int l = blockIdx.x;
  const int nbins = (STAGE == 1) ? NB1 : NB2;
  const u32* hl = hist + l * nbins;
  __shared__ u32 part[256];
  int tid = threadIdx.x;
  int chunk = nbins >> 8;
  u32 sm = 0;
  for (int i = tid * chunk; i < (tid + 1) * chunk; ++i) sm += hl[i];
  part[tid] = sm;
  __syncthreads();
  if (tid == 0) {
    u32 r = (STAGE == 1) ? (l == 0 ? r0 : (l == 1 ? r1 : r2)) : meta[l * 8 + 1];
    u32 c = 0; int t = 0;
    for (; t < 256; ++t) { if (c + part[t] > r) break; c += part[t]; }
    u32 rr = r - c;
    int bin = t * chunk;
    for (;;) { u32 hv = hl[bin]; if (rr < hv) break; rr -= hv; ++bin; }
    if (STAGE == 1) { meta[l * 8 + 0] = (u32)bin; meta[l * 8 + 1] = rr; }
    else           { meta[l * 8 + 2] = (u32)bin; meta[l * 8 + 3] = rr; }
  }
}

// Fused mask+cast build: 22-bit prefix > t22 -> bf16(w); < -> 0; == -> 0 + candidate.
__global__ void build_k(const float4* __restrict__ w, const uint4* __restrict__ s,
                        ushort4* __restrict__ wb, int n4,
                        u32* __restrict__ meta, uint2* __restrict__ cand) {
  u32 t22 = (meta[0] << 12) | meta[2];
  int stride = gridDim.x * blockDim.x;
  for (int i = blockIdx.x * blockDim.x + threadIdx.x; i < n4; i += stride) {
    uint4 sv = s[i];
    float4 wv = w[i];
    u32 k0 = sv.x & KEYMASK, k1 = sv.y & KEYMASK, k2 = sv.z & KEYMASK, k3 = sv.w & KEYMASK;
    ushort4 o;
    o.x = ((k0 >> 9) > t22) ? f2bf(wv.x) : (u16)0;
    o.y = ((k1 >> 9) > t22) ? f2bf(wv.y) : (u16)0;
    o.z = ((k2 >> 9) > t22) ? f2bf(wv.z) : (u16)0;
    o.w = ((k3 >> 9) > t22) ? f2bf(wv.w) : (u16)0;
    wb[i] = o;
    u32 base = (u32)i * 4u;
    if ((k0 >> 9) == t22) { u32 p = atomicAdd(&meta[4], 1u); if (p < CANDCAP) cand[p] = make_uint2(k0, base); }
    if ((k1 >> 9) == t22) { u32 p = atomicAdd(&meta[4], 1u); if (p < CANDCAP) cand[p] = make_uint2(k1, base + 1u); }
    if ((k2 >> 9) == t22) { u32 p = atomicAdd(&meta[4], 1u); if (p < CANDCAP) cand[p] = make_uint2(k2, base + 2u); }
    if ((k3 >> 9) == t22) { u32 p = atomicAdd(&meta[4], 1u); if (p < CANDCAP) cand[p] = make_uint2(k3, base + 3u); }
  }
}

// Exact low-9-bit select among candidates + stable-argsort tie semantics:
// among keys equal to the exact threshold, the q with smallest flat index stay 0.
__global__ void finalize_k(u16* __restrict__ wb, const float* __restrict__ w,
                           const u32* __restrict__ meta, const uint2* __restrict__ cand) {
  __shared__ u32 h[512];
  __shared__ u32 tie[TIECAP];
  __shared__ u32 tcnt, t9s, qs;
  int tid = threadIdx.x;
  for (int i = tid; i < 512; i += blockDim.x) h[i] = 0;
  if (tid == 0) tcnt = 0;
  __syncthreads();
  u32 m = meta[4]; if (m > CANDCAP) m = CANDCAP;
  for (u32 i = tid; i < m; i += blockDim.x) atomicAdd(&h[cand[i].x & 0x1ffu], 1u);
  __syncthreads();
  if (tid == 0) {
    u32 r = meta[3];
    u32 c = 0; int bin = 0;
    for (;;) { u32 hv = h[bin]; if (c + hv > r) break; c += hv; ++bin; }
    t9s = (u32)bin; qs = r - c;
  }
  __syncthreads();
  u32 t9 = t9s, q = qs;
  for (u32 i = tid; i < m; i += blockDim.x) {
    uint2 cd = cand[i];
    u32 k9 = cd.x & 0x1ffu;
    if (k9 > t9) wb[cd.y] = f2bf(w[cd.y]);
    else if (k9 == t9) { u32 p = atomicAdd(&tcnt, 1u); if (p < TIECAP) tie[p] = cd.y; }
  }
  __syncthreads();
  u32 tc = tcnt; if (tc > TIECAP) tc = TIECAP;
  for (u32 i = tid; i < tc; i += blockDim.x) {
    u32 my = tie[i];
    u32 rk = 0;
    for (u32 j = 0; j < tc; ++j) rk += (tie[j] < my) ? 1u : 0u;
    if (rk >= q) wb[my] = f2bf(w[my]);
  }
}

// ============ 256x256 tile GEMM, BK=64, 8 waves, counted-vmcnt pipeline ============
__global__ __launch_bounds__(512, 2) void gemm256(
    const u16* __restrict__ A, const u16* __restrict__ B,
    const float* __restrict__ bias, u16* __restrict__ C,
    int N, int K) {
  __shared__ __align__(16) u16 As[2][256 * 64];
  __shared__ __align__(16) u16 Bs[2][256 * 64];
  const int tid = threadIdx.x;
  const int lane = tid & 63;
  const int wv = tid >> 6;
  const int wm = wv >> 2;
  const int wn = wv & 3;
  const int fr = lane & 15;
  const int fkg = lane >> 4;
  const long brow = (long)blockIdx.y * 256;
  const long bcol = (long)blockIdx.x * 256;

  const int srow = tid >> 3;
  const int sgran = (tid & 7) ^ (srow & 7);
  const u16* pA[4];
  const u16* pB[4];
#pragma unroll
  for (int j = 0; j < 4; ++j) {
    pA[j] = A + (size_t)(brow + j * 64 + srow) * (size_t)K + sgran * 8;
    pB[j] = B + (size_t)(bcol + j * 64 + srow) * (size_t)K + sgran * 8;
  }
  char* lA[2]; char* lB[2];
  lA[0] = (char*)&As[0][0] + wv * 1024;
  lA[1] = (char*)&As[1][0] + wv * 1024;
  lB[0] = (char*)&Bs[0][0] + wv * 1024;
  lB[1] = (char*)&Bs[1][0] + wv * 1024;

  const int NT = K >> 6;

#pragma unroll
  for (int j = 0; j < 4; ++j) { async16(lA[0] + j * 8192, pA[j]); async16(lB[0] + j * 8192, pB[j]); }
#pragma unroll
  for (int j = 0; j < 4; ++j) { async16(lA[1] + j * 8192, pA[j] + 64); async16(lB[1] + j * 8192, pB[j] + 64); }

  f32x4 acc[8][4] = {};
  const int kswz = (fr & 7) << 4;

  for (int t = 0; t < NT; ++t) {
    if (t < NT - 1) { asm volatile("s_waitcnt vmcnt(8)" ::: "memory"); }
    else           { asm volatile("s_waitcnt vmcnt(0)" ::: "memory"); }
    __builtin_amdgcn_sched_barrier(0);
    __builtin_amdgcn_s_barrier();
    __builtin_amdgcn_sched_barrier(0);

    const char* Ab = (const char*)&As[t & 1][0];
    const char* Bb = (const char*)&Bs[t & 1][0];
#pragma unroll
    for (int ks = 0; ks < 2; ++ks) {
      const int ko = (ks * 64 + fkg * 16) ^ kswz;
      s16x8 a[8], b[4];
#pragma unroll
      for (int mf = 0; mf < 8; ++mf)
        a[mf] = *(const s16x8*)(Ab + (wm * 128 + mf * 16 + fr) * 128 + ko);
#pragma unroll
      for (int nf = 0; nf < 4; ++nf)
        b[nf] = *(const s16x8*)(Bb + (wn * 64 + nf * 16 + fr) * 128 + ko);
      __builtin_amdgcn_s_setprio(1);
#pragma unroll
      for (int mf = 0; mf < 8; ++mf)
#pragma unroll
        for (int nf = 0; nf < 4; ++nf)
          acc[mf][nf] = mfma_bf16(a[mf], b[nf], acc[mf][nf]);
      __builtin_amdgcn_s_setprio(0);
    }

    __builtin_amdgcn_sched_barrier(0);
    __builtin_amdgcn_s_barrier();
    __builtin_amdgcn_sched_barrier(0);

    if (t + 2 < NT) {
      const int kt = (t + 2) << 6;
      char* dA = lA[t & 1]; char* dB = lB[t & 1];
#pragma unroll
      for (int j = 0; j < 4; ++j) { async16(dA + j * 8192, pA[j] + kt); async16(dB + j * 8192, pB[j] + kt); }
    }
  }

#pragma unroll
  for (int nf = 0; nf < 4; ++nf) {
    const long col = bcol + wn * 64 + nf * 16 + fr;
    const float bv = bias[col];
#pragma unroll
    for (int mf = 0; mf < 8; ++mf) {
      const long row0 = brow + wm * 128 + mf * 16 + fkg * 4;
#pragma unroll
      for (int i = 0; i < 4; ++i) {
        float v = fmaxf(acc[mf][nf][i] + bv, 0.0f);
        C[(row0 + i) * (long)N + col] = f2bf(v);
      }
    }
  }
}

// ---------------- 128x128 GEMM (layer 3: N=1000->1024) ----------------
template <int RELU, int CBF16>
__global__ __launch_bounds__(256) void gemm_bt(
    const u16* __restrict__ A, const u16* __restrict__ B,
    const float* __restrict__ bias, void* __restrict__ Cv,
    int Ntrue, int K) {
  __shared__ __align__(16) u16 As[128 * 32];
  __shared__ __align__(16) u16 Bs[128 * 32];
  const int tid = threadIdx.x;
  const int lane = tid & 63;
  const int wv = tid >> 6;
  const long brow = (long)blockIdx.y * 128;
  const long bcol = (long)blockIdx.x * 128;
  const int wm = (wv >> 1) * 64;
  const int wn = (wv & 1) * 64;

  const u16* gA0 = A + (brow + (tid >> 2)) * (long)K + (tid & 3) * 8;
  const u16* gA1 = gA0 + (size_t)64 * K;
  const u16* gB0 = B + (bcol + (tid >> 2)) * (long)K + (tid & 3) * 8;
  const u16* gB1 = gB0 + (size_t)64 * K;
  char* lA0 = (char*)As + wv * 1024;
  char* lA1 = (char*)As + 4096 + wv * 1024;
  char* lB0 = (char*)Bs + wv * 1024;
  char* lB1 = (char*)Bs + 4096 + wv * 1024;

  f32x4 acc[4][4] = {};
  const int fr = lane & 15;
  const int fk = (lane >> 4) * 8;

  for (int kt = 0; kt < K; kt += 32) {
    async16(lA0, gA0 + kt);
    async16(lA1, gA1 + kt);
    async16(lB0, gB0 + kt);
    async16(lB1, gB1 + kt);
    __syncthreads();
    s16x8 a[4], b[4];
#pragma unroll
    for (int m = 0; m < 4; ++m) a[m] = *(const s16x8*)&As[(wm + m * 16 + fr) * 32 + fk];
#pragma unroll
    for (int n = 0; n < 4; ++n) b[n] = *(const s16x8*)&Bs[(wn + n * 16 + fr) * 32 + fk];
#pragma unroll
    for (int m = 0; m < 4; ++m)
#pragma unroll
      for (int n = 0; n < 4; ++n)
        acc[m][n] = mfma_bf16(a[m], b[n], acc[m][n]);
    __syncthreads();
  }

  const long col0 = bcol + wn + fr;
  const long row0 = brow + wm + ((lane >> 4) << 2);
#pragma unroll
  for (int n = 0; n < 4; ++n) {
    long col = col0 + n * 16;
    if (!CBF16 && col >= Ntrue) continue;
    float bv = bias[col];
#pragma unroll
    for (int m = 0; m < 4; ++m) {
#pragma unroll
      for (int i = 0; i < 4; ++i) {
        float v = acc[m][n][i] + bv;
        if (RELU) v = fmaxf(v, 0.0f);
        long off = (row0 + m * 16 + i) * (long)Ntrue + col;
        if (CBF16) ((u16*)Cv)[off] = f2bf(v);
        else ((float*)Cv)[off] = v;
      }
    }
  }
}

// ---------------- launch ----------------
extern "C" void kernel_launch(void* const* d_in, const int* in_sizes, int n_in,
                              void* d_out, int out_size, void* d_ws, size_t ws_size,
                              hipStream_t stream) {
  const float* x  = (const float*)d_in[0];
  const float* w1 = (const float*)d_in[1];
  const float* s1 = (const float*)d_in[2];
  const float* b1 = (const float*)d_in[3];
  const float* w2 = (const float*)d_in[4];
  const float* s2 = (const float*)d_in[5];
  const float* b2 = (const float*)d_in[6];
  const float* w3 = (const float*)d_in[7];
  const float* s3 = (const float*)d_in[8];
  const float* b3 = (const float*)d_in[9];
  float* out = (float*)d_out;

  const int n1 = 4096 * 2048, n2 = 4096 * 4096, n3 = 1000 * 4096;

  char* ws = (char*)d_ws;
  u32*   meta = (u32*)ws;                  // 3 x 8 u32
  u32*   gh1  = (u32*)(ws + 0x1000);       // 3 x 1024
  u32*   gh2  = (u32*)(ws + 0x4000);       // 3 x 4096, ends 0x10000
  uint2* cand = (uint2*)(ws + 0x10000);    // 3 x 65536 x 8B, ends 0x190000
  u16* Wb = (u16*)(ws + (2l  << 20));      // 32 MiB, reused per layer
  u16* H1 = (u16*)(ws + (34l << 20));      // 32 MiB
  u16* H2 = (u16*)(ws + (66l << 20));      // 32 MiB
  u16* Xb = (u16*)(ws + (66l << 20));      // 16 MiB, aliases H2 (dead before GEMM2 writes H2)

  // x -> bf16
  f32_to_bf16_k<<<1024, 256, 0, stream>>>((const float4*)x, (ushort4*)Xb, n1 / 4);

  // fused selection: hists + selects for all 3 layers
  hipMemsetAsync(ws, 0, 0x10000, stream);
  hist1_k<<<256, 1024, 0, stream>>>((const uint4*)s1, n1 / 4, (const uint4*)s2, n2 / 4,
                                    (const uint4*)s3, n3 / 4, gh1);
  select_k<1><<<3, 256, 0, stream>>>(gh1, meta, (u32)(n1 / 2), (u32)(n2 / 2), (u32)(n3 / 2));
  hist2_k<<<256, 1024, 0, stream>>>((const uint4*)s1, n1 / 4, (const uint4*)s2, n2 / 4,
                                    (const uint4*)s3, n3 / 4, gh2, meta);
  select_k<2><<<3, 256, 0, stream>>>(gh2, meta, 0, 0, 0);

  // Layer 1: (4096x2048) -> 4096, relu, bf16
  build_k<<<512, 256, 0, stream>>>((const float4*)w1, (const uint4*)s1, (ushort4*)Wb,
                                   n1 / 4, meta + 0, cand + 0);
  finalize_k<<<1, 1024, 0, stream>>>(Wb, w1, meta + 0, cand + 0);
  gemm256<<<dim3(16, 16), 512, 0, stream>>>(Xb, Wb, b1, H1, 4096, 2048);

  // Layer 2: 4096 -> 4096, relu, bf16
  build_k<<<512, 256, 0, stream>>>((const float4*)w2, (const uint4*)s2, (ushort4*)Wb,
                                   n2 / 4, meta + 8, cand + CANDCAP);
  finalize_k<<<1, 1024, 0, stream>>>(Wb, w2, meta + 8, cand + CANDCAP);
  gemm256<<<dim3(16, 16), 512, 0, stream>>>(H1, Wb, b2, H2, 4096, 4096);

  // Layer 3: 4096 -> 1000 (padded to 1024 rows), fp32 out
  build_k<<<512, 256, 0, stream>>>((const float4*)w3, (const uint4*)s3, (ushort4*)Wb,
                                   n3 / 4, meta + 16, cand + 2 * CANDCAP);
  finalize_k<<<1, 1024, 0, stream>>>(Wb, w3, meta + 16, cand + 2 * CANDCAP);
  hipMemsetAsync((char*)Wb + (size_t)1000 * 4096 * 2, 0, (size_t)24 * 4096 * 2, stream);
  gemm_bt<0, 0><<<dim3(8, 32), 256, 0, stream>>>(H2, Wb, b3, out, 1000, 4096);
}

// Round 4
// 455.804 us; speedup vs baseline: 1.6352x; 1.0772x over previous
//
#include <hip/hip_runtime.h>

typedef unsigned int u32;
typedef unsigned short u16;
typedef short s16x8 __attribute__((ext_vector_type(8)));
typedef __bf16 bf16x8 __attribute__((ext_vector_type(8)));
typedef float f32x4 __attribute__((ext_vector_type(4)));

#define KEYMASK 0x7fffffffu
#define NB1 1024
#define NB2 4096
#define CANDCAP 65536
#define TIECAP 2048

__device__ __forceinline__ u16 f2bf(float f) {
  u32 u = __builtin_bit_cast(u32, f);
  return (u16)((u + 0x7fffu + ((u >> 16) & 1u)) >> 16);
}

// Handles either builtin signature (short8 or __bf16x8) across ROCm versions.
struct ABFrag {
  s16x8 v;
  __device__ operator s16x8() const { return v; }
  __device__ operator bf16x8() const { return __builtin_bit_cast(bf16x8, v); }
};

__device__ __forceinline__ f32x4 mfma_bf16(s16x8 a, s16x8 b, f32x4 c) {
  return __builtin_amdgcn_mfma_f32_16x16x32_bf16(ABFrag{a}, ABFrag{b}, c, 0, 0, 0);
}

__device__ __forceinline__ void async16(void* lds, const void* g) {
  __builtin_amdgcn_global_load_lds(
      (__attribute__((address_space(1))) void*)(const_cast<void*>(g)),
      (__attribute__((address_space(3))) void*)lds, 16, 0, 0);
}

// ---------------- conversion ----------------
__global__ void f32_to_bf16_k(const float4* __restrict__ in, ushort4* __restrict__ out, int n4) {
  int stride = gridDim.x * blockDim.x;
  for (int i = blockIdx.x * blockDim.x + threadIdx.x; i < n4; i += stride) {
    float4 v = in[i];
    ushort4 o;
    o.x = f2bf(v.x); o.y = f2bf(v.y); o.z = f2bf(v.z); o.w = f2bf(v.w);
    out[i] = o;
  }
}

// ================= fused 3-layer radix selection =================
// meta layout per layer (8 u32): [0]=selA(10b) [1]=r1 [2]=selB(12b) [3]=r2 [4]=candCount

__global__ void hist1_k(const uint4* __restrict__ sa, int na,
                        const uint4* __restrict__ sb, int nb,
                        const uint4* __restrict__ sc, int nc,
                        u32* __restrict__ gh) {
  __shared__ u32 h[3 * NB1 * 4];  // 48KB: [l][bin][replica]
  for (int i = threadIdx.x; i < 3 * NB1 * 4; i += blockDim.x) h[i] = 0;
  __syncthreads();
  const int rep = threadIdx.x & 3;
  const uint4* sp[3] = {sa, sb, sc};
  int nn[3] = {na, nb, nc};
  int stride = gridDim.x * blockDim.x;
  for (int l = 0; l < 3; ++l) {
    const uint4* s = sp[l];
    int n4 = nn[l];
    u32* hl = &h[l * NB1 * 4 + rep];
    for (int i = blockIdx.x * blockDim.x + threadIdx.x; i < n4; i += stride) {
      uint4 v = s[i];
      atomicAdd(&hl[((v.x & KEYMASK) >> 21) * 4], 1u);
      atomicAdd(&hl[((v.y & KEYMASK) >> 21) * 4], 1u);
      atomicAdd(&hl[((v.z & KEYMASK) >> 21) * 4], 1u);
      atomicAdd(&hl[((v.w & KEYMASK) >> 21) * 4], 1u);
    }
  }
  __syncthreads();
  for (int i = threadIdx.x; i < 3 * NB1; i += blockDim.x) {
    u32 c = h[i * 4] + h[i * 4 + 1] + h[i * 4 + 2] + h[i * 4 + 3];
    if (c) atomicAdd(&gh[i], c);
  }
}

__global__ void hist2_k(const uint4* __restrict__ sa, int na,
                        const uint4* __restrict__ sb, int nb,
                        const uint4* __restrict__ sc, int nc,
                        u32* __restrict__ gh, const u32* __restrict__ meta) {
  __shared__ u32 h[3 * NB2];  // 48KB
  for (int i = threadIdx.x; i < 3 * NB2; i += blockDim.x) h[i] = 0;
  __syncthreads();
  const uint4* sp[3] = {sa, sb, sc};
  int nn[3] = {na, nb, nc};
  int stride = gridDim.x * blockDim.x;
  for (int l = 0; l < 3; ++l) {
    const uint4* s = sp[l];
    int n4 = nn[l];
    u32 selA = meta[l * 8 + 0];
    u32* hl = &h[l * NB2];
    for (int i = blockIdx.x * blockDim.x + threadIdx.x; i < n4; i += stride) {
      uint4 v = s[i];
      u32 k;
      k = v.x & KEYMASK; if ((k >> 21) == selA) atomicAdd(&hl[(k >> 9) & 0xfffu], 1u);
      k = v.y & KEYMASK; if ((k >> 21) == selA) atomicAdd(&hl[(k >> 9) & 0xfffu], 1u);
      k = v.z & KEYMASK; if ((k >> 21) == selA) atomicAdd(&hl[(k >> 9) & 0xfffu], 1u);
      k = v.w & KEYMASK; if ((k >> 21) == selA) atomicAdd(&hl[(k >> 9) & 0xfffu], 1u);
    }
  }
  __syncthreads();
  for (int i = threadIdx.x; i < 3 * NB2; i += blockDim.x) {
    u32 c = h[i];
    if (c) atomicAdd(&gh[i], c);
  }
}

template <int STAGE>
__global__ void select_k(const u32* __restrict__ hist, u32* __restrict__ meta,
                         u32 r0, u32 r1, u32 r2) {
  const int l = blockIdx.x;
  const int nbins = (STAGE == 1) ? NB1 : NB2;
  const u32* hl = hist + l * nbins;
  __shared__ u32 part[256];
  int tid = threadIdx.x;
  int chunk = nbins >> 8;
  u32 sm = 0;
  for (int i = tid * chunk; i < (tid + 1) * chunk; ++i) sm += hl[i];
  part[tid] = sm;
  __syncthreads();
  if (tid == 0) {
    u32 r = (STAGE == 1) ? (l == 0 ? r0 : (l == 1 ? r1 : r2)) : meta[l * 8 + 1];
    u32 c = 0; int t = 0;
    for (; t < 256; ++t) { if (c + part[t] > r) break; c += part[t]; }
    u32 rr = r - c;
    int bin = t * chunk;
    for (;;) { u32 hv = hl[bin]; if (rr < hv) break; rr -= hv; ++bin; }
    if (STAGE == 1) { meta[l * 8 + 0] = (u32)bin; meta[l * 8 + 1] = rr; }
    else           { meta[l * 8 + 2] = (u32)bin; meta[l * 8 + 3] = rr; }
  }
}

// Fused mask+cast build: 22-bit prefix > t22 -> bf16(w); < -> 0; == -> 0 + candidate.
__global__ void build_k(const float4* __restrict__ w, const uint4* __restrict__ s,
                        ushort4* __restrict__ wb, int n4,
                        u32* __restrict__ meta, uint2* __restrict__ cand) {
  u32 t22 = (meta[0] << 12) | meta[2];
  int stride = gridDim.x * blockDim.x;
  for (int i = blockIdx.x * blockDim.x + threadIdx.x; i < n4; i += stride) {
    uint4 sv = s[i];
    float4 wv = w[i];
    u32 k0 = sv.x & KEYMASK, k1 = sv.y & KEYMASK, k2 = sv.z & KEYMASK, k3 = sv.w & KEYMASK;
    ushort4 o;
    o.x = ((k0 >> 9) > t22) ? f2bf(wv.x) : (u16)0;
    o.y = ((k1 >> 9) > t22) ? f2bf(wv.y) : (u16)0;
    o.z = ((k2 >> 9) > t22) ? f2bf(wv.z) : (u16)0;
    o.w = ((k3 >> 9) > t22) ? f2bf(wv.w) : (u16)0;
    wb[i] = o;
    u32 base = (u32)i * 4u;
    if ((k0 >> 9) == t22) { u32 p = atomicAdd(&meta[4], 1u); if (p < CANDCAP) cand[p] = make_uint2(k0, base); }
    if ((k1 >> 9) == t22) { u32 p = atomicAdd(&meta[4], 1u); if (p < CANDCAP) cand[p] = make_uint2(k1, base + 1u); }
    if ((k2 >> 9) == t22) { u32 p = atomicAdd(&meta[4], 1u); if (p < CANDCAP) cand[p] = make_uint2(k2, base + 2u); }
    if ((k3 >> 9) == t22) { u32 p = atomicAdd(&meta[4], 1u); if (p < CANDCAP) cand[p] = make_uint2(k3, base + 3u); }
  }
}

// Exact low-9-bit select among candidates + stable-argsort tie semantics.
__global__ void finalize_k(u16* __restrict__ wb, const float* __restrict__ w,
                           const u32* __restrict__ meta, const uint2* __restrict__ cand) {
  __shared__ u32 h[512];
  __shared__ u32 tie[TIECAP];
  __shared__ u32 tcnt, t9s, qs;
  int tid = threadIdx.x;
  for (int i = tid; i < 512; i += blockDim.x) h[i] = 0;
  if (tid == 0) tcnt = 0;
  __syncthreads();
  u32 m = meta[4]; if (m > CANDCAP) m = CANDCAP;
  for (u32 i = tid; i < m; i += blockDim.x) atomicAdd(&h[cand[i].x & 0x1ffu], 1u);
  __syncthreads();
  if (tid == 0) {
    u32 r = meta[3];
    u32 c = 0; int bin = 0;
    for (;;) { u32 hv = h[bin]; if (c + hv > r) break; c += hv; ++bin; }
    t9s = (u32)bin; qs = r - c;
  }
  __syncthreads();
  u32 t9 = t9s, q = qs;
  for (u32 i = tid; i < m; i += blockDim.x) {
    uint2 cd = cand[i];
    u32 k9 = cd.x & 0x1ffu;
    if (k9 > t9) wb[cd.y] = f2bf(w[cd.y]);
    else if (k9 == t9) { u32 p = atomicAdd(&tcnt, 1u); if (p < TIECAP) tie[p] = cd.y; }
  }
  __syncthreads();
  u32 tc = tcnt; if (tc > TIECAP) tc = TIECAP;
  for (u32 i = tid; i < tc; i += blockDim.x) {
    u32 my = tie[i];
    u32 rk = 0;
    for (u32 j = 0; j < tc; ++j) rk += (tie[j] < my) ? 1u : 0u;
    if (rk >= q) wb[my] = f2bf(w[my]);
  }
}

// ======== 256x256 GEMM, BK=64, 8 waves, 4-phase counted-vmcnt pipeline ========
// C = relu(A(MxK) * B(NxK)^T + bias), bf16 in/out, fp32 acc.
// A LDS layout (per K-tile buffer): row-permuted so phase q reads contiguous
// chunk q: LDSrow = q*64 + half*32 + r  <->  global tile row = half*128 + q*32 + r.
// B LDS layout: linear [256][64]. Both XOR-swizzled per 16B granule: granule
// g of row R holds global granule g^(R&7).
// Stage schedule per iter t (read buf p=t&1, tiles t+2 staged into p):
//   ph0: A3(t+1)->buf p^1 | ph1: A0,B0(t+2) | ph2: A1,B1(t+2) | ph3: A2,B2,B3(t+2)
// Waits: vmcnt(8) @ph0 (tile t minus A3 landed), vmcnt(12) @ph3 (A3(t) landed).
// Tail stages clamp K-offset (garbage, never read) to keep counts uniform.
__global__ __launch_bounds__(512) void gemm256(
    const u16* __restrict__ A, const u16* __restrict__ B,
    const float* __restrict__ bias, u16* __restrict__ C,
    int N, int K) {
  __shared__ __align__(16) u16 As[2][256 * 64];
  __shared__ __align__(16) u16 Bs[2][256 * 64];
  const int tid = threadIdx.x;
  const int lane = tid & 63;
  const int wv = tid >> 6;
  const int wm = wv >> 2;        // 0..1
  const int wn = wv & 3;         // 0..3
  const int fr = lane & 15;
  const int fkg = lane >> 4;     // 0..3
  const long brow = (long)blockIdx.y * 256;
  const long bcol = (long)blockIdx.x * 256;

  // staging thread mapping: chunk-local row = tid>>3, granule = tid&7
  const int sr6 = tid >> 3;                       // 0..63
  const int sgr = ((tid & 7) ^ (sr6 & 7)) << 3;   // inverse-swizzled src elem offset
  const int ha = tid >> 8;                        // A half (0/1)
  const int ra = sr6 & 31;                        // A row within quarter
  const u16* pAq[4];
  const u16* pBc[4];
#pragma unroll
  for (int q = 0; q < 4; ++q)
    pAq[q] = A + (size_t)(brow + ha * 128 + q * 32 + ra) * (size_t)K + sgr;
#pragma unroll
  for (int c = 0; c < 4; ++c)
    pBc[c] = B + (size_t)(bcol + c * 64 + sr6) * (size_t)K + sgr;

  f32x4 acc[8][4] = {};
  s16x8 bfr[4][2];

  // swizzled granule byte offsets for ds_read (desired granule kk*4+fkg)
  const int swz0 = ((0 + fkg) ^ (fr & 7)) * 16;
  const int swz1 = ((4 + fkg) ^ (fr & 7)) * 16;

  const int aRowBase = wm * 32 + fr;       // + q*64 + j*16 -> LDS row
  const int bRowBase = wn * 64 + fr;       // + nf*16

  // ---- prologue: tile0 {A0,A1,A2,B0..B3,A3}, tile1 {A0,A1,A2,B0..B3} ----
  {
    char* a0 = (char*)&As[0][0] + wv * 1024;
    char* b0 = (char*)&Bs[0][0] + wv * 1024;
    async16(a0 + 0 * 8192, pAq[0]); async16(a0 + 1 * 8192, pAq[1]); async16(a0 + 2 * 8192, pAq[2]);
    async16(b0 + 0 * 8192, pBc[0]); async16(b0 + 1 * 8192, pBc[1]);
    async16(b0 + 2 * 8192, pBc[2]); async16(b0 + 3 * 8192, pBc[3]);
    async16(a0 + 3 * 8192, pAq[3]);
    char* a1 = (char*)&As[1][0] + wv * 1024;
    char* b1 = (char*)&Bs[1][0] + wv * 1024;
    async16(a1 + 0 * 8192, pAq[0] + 64); async16(a1 + 1 * 8192, pAq[1] + 64); async16(a1 + 2 * 8192, pAq[2] + 64);
    async16(b1 + 0 * 8192, pBc[0] + 64); async16(b1 + 1 * 8192, pBc[1] + 64);
    async16(b1 + 2 * 8192, pBc[2] + 64); async16(b1 + 3 * 8192, pBc[3] + 64);
  }

  const int NT = K >> 6;   // requires K >= 128

  for (int t = 0; t < NT; ++t) {
    const int p = t & 1;
    const char* Ab = (const char*)&As[p][0];
    const char* Bb = (const char*)&Bs[p][0];
    char* sA = (char*)&As[p][0] + wv * 1024;
    char* sB = (char*)&Bs[p][0] + wv * 1024;
    char* sAo = (char*)&As[p ^ 1][0] + wv * 1024;
    const int k1 = (t + 1 < NT ? t + 1 : 0) << 6;
    const int k2 = (t + 2 < NT ? t + 2 : 0) << 6;

    // ---------------- phase 0 ----------------
    asm volatile("s_waitcnt vmcnt(8)" ::: "memory");
    __builtin_amdgcn_sched_barrier(0);
    __builtin_amdgcn_s_barrier();
    __builtin_amdgcn_sched_barrier(0);
    {
#pragma unroll
      for (int nf = 0; nf < 4; ++nf) {
        const char* rb = Bb + (bRowBase + nf * 16) * 128;
        bfr[nf][0] = *(const s16x8*)(rb + swz0);
        bfr[nf][1] = *(const s16x8*)(rb + swz1);
      }
      s16x8 a_[2][2];
#pragma unroll
      for (int j = 0; j < 2; ++j) {
        const char* rb = Ab + (0 * 64 + aRowBase + j * 16) * 128;
        a_[j][0] = *(const s16x8*)(rb + swz0);
        a_[j][1] = *(const s16x8*)(rb + swz1);
      }
      async16(sAo + 3 * 8192, pAq[3] + k1);
      __builtin_amdgcn_s_setprio(1);
#pragma unroll
      for (int j = 0; j < 2; ++j)
#pragma unroll
        for (int kk = 0; kk < 2; ++kk)
#pragma unroll
          for (int nf = 0; nf < 4; ++nf)
            acc[j][nf] = mfma_bf16(a_[j][kk], bfr[nf][kk], acc[j][nf]);
      __builtin_amdgcn_s_setprio(0);
    }

    // ---------------- phase 1 ----------------
    __builtin_amdgcn_sched_barrier(0);
    __builtin_amdgcn_s_barrier();
    __builtin_amdgcn_sched_barrier(0);
    {
      s16x8 a_[2][2];
#pragma unroll
      for (int j = 0; j < 2; ++j) {
        const char* rb = Ab + (1 * 64 + aRowBase + j * 16) * 128;
        a_[j][0] = *(const s16x8*)(rb + swz0);
        a_[j][1] = *(const s16x8*)(rb + swz1);
      }
      async16(sA + 0 * 8192, pAq[0] + k2);
      async16(sB + 0 * 8192, pBc[0] + k2);
      __builtin_amdgcn_s_setprio(1);
#pragma unroll
      for (int j = 0; j < 2; ++j)
#pragma unroll
        for (int kk = 0; kk < 2; ++kk)
#pragma unroll
          for (int nf = 0; nf < 4; ++nf)
            acc[2 + j][nf] = mfma_bf16(a_[j][kk], bfr[nf][kk], acc[2 + j][nf]);
      __builtin_amdgcn_s_setprio(0);
    }

    // ---------------- phase 2 ----------------
    __builtin_amdgcn_sched_barrier(0);
    __builtin_amdgcn_s_barrier();
    __builtin_amdgcn_sched_barrier(0);
    {
      s16x8 a_[2][2];
#pragma unroll
      for (int j = 0; j < 2; ++j) {
        const char* rb = Ab + (2 * 64 + aRowBase + j * 16) * 128;
        a_[j][0] = *(const s16x8*)(rb + swz0);
        a_[j][1] = *(const s16x8*)(rb + swz1);
      }
      async16(sA + 1 * 8192, pAq[1] + k2);
      async16(sB + 1 * 8192, pBc[1] + k2);
      __builtin_amdgcn_s_setprio(1);
#pragma unroll
      for (int j = 0; j < 2; ++j)
#pragma unroll
        for (int kk = 0; kk < 2; ++kk)
#pragma unroll
          for (int nf = 0; nf < 4; ++nf)
            acc[4 + j][nf] = mfma_bf16(a_[j][kk], bfr[nf][kk], acc[4 + j][nf]);
      __builtin_amdgcn_s_setprio(0);
    }

    // ---------------- phase 3 ----------------
    asm volatile("s_waitcnt vmcnt(12)" ::: "memory");
    __builtin_amdgcn_sched_barrier(0);
    __builtin_amdgcn_s_barrier();
    __builtin_amdgcn_sched_barrier(0);
    {
      s16x8 a_[2][2];
#pragma unroll
      for (int j = 0; j < 2; ++j) {
        const char* rb = Ab + (3 * 64 + aRowBase + j * 16) * 128;
        a_[j][0] = *(const s16x8*)(rb + swz0);
        a_[j][1] = *(const s16x8*)(rb + swz1);
      }
      async16(sA + 2 * 8192, pAq[2] + k2);
      async16(sB + 2 * 8192, pBc[2] + k2);
      async16(sB + 3 * 8192, pBc[3] + k2);
      __builtin_amdgcn_s_setprio(1);
#pragma unroll
      for (int j = 0; j < 2; ++j)
#pragma unroll
        for (int kk = 0; kk < 2; ++kk)
#pragma unroll
          for (int nf = 0; nf < 4; ++nf)
            acc[6 + j][nf] = mfma_bf16(a_[j][kk], bfr[nf][kk], acc[6 + j][nf]);
      __builtin_amdgcn_s_setprio(0);
    }
  }

  asm volatile("s_waitcnt vmcnt(0)" ::: "memory");  // drain clamped tail stages

  // epilogue: C/D layout col=lane&15, row=(lane>>4)*4+i (m89-verified)
#pragma unroll
  for (int nf = 0; nf < 4; ++nf) {
    const long col = bcol + wn * 64 + nf * 16 + fr;
    const float bv = bias[col];
#pragma unroll
    for (int mf = 0; mf < 8; ++mf) {
      const long row0 = brow + wm * 128 + mf * 16 + fkg * 4;
#pragma unroll
      for (int i = 0; i < 4; ++i) {
        float v = fmaxf(acc[mf][nf][i] + bv, 0.0f);
        C[(row0 + i) * (long)N + col] = f2bf(v);
      }
    }
  }
}

// ---------------- 128x128 GEMM (layer 3: N=1000->1024) ----------------
template <int RELU, int CBF16>
__global__ __launch_bounds__(256) void gemm_bt(
    const u16* __restrict__ A, const u16* __restrict__ B,
    const float* __restrict__ bias, void* __restrict__ Cv,
    int Ntrue, int K) {
  __shared__ __align__(16) u16 As[128 * 32];
  __shared__ __align__(16) u16 Bs[128 * 32];
  const int tid = threadIdx.x;
  const int lane = tid & 63;
  const int wv = tid >> 6;
  const long brow = (long)blockIdx.y * 128;
  const long bcol = (long)blockIdx.x * 128;
  const int wm = (wv >> 1) * 64;
  const int wn = (wv & 1) * 64;

  const u16* gA0 = A + (brow + (tid >> 2)) * (long)K + (tid & 3) * 8;
  const u16* gA1 = gA0 + (size_t)64 * K;
  const u16* gB0 = B + (bcol + (tid >> 2)) * (long)K + (tid & 3) * 8;
  const u16* gB1 = gB0 + (size_t)64 * K;
  char* lA0 = (char*)As + wv * 1024;
  char* lA1 = (char*)As + 4096 + wv * 1024;
  char* lB0 = (char*)Bs + wv * 1024;
  char* lB1 = (char*)Bs + 4096 + wv * 1024;

  f32x4 acc[4][4] = {};
  const int fr = lane & 15;
  const int fk = (lane >> 4) * 8;

  for (int kt = 0; kt < K; kt += 32) {
    async16(lA0, gA0 + kt);
    async16(lA1, gA1 + kt);
    async16(lB0, gB0 + kt);
    async16(lB1, gB1 + kt);
    __syncthreads();
    s16x8 a[4], b[4];
#pragma unroll
    for (int m = 0; m < 4; ++m) a[m] = *(const s16x8*)&As[(wm + m * 16 + fr) * 32 + fk];
#pragma unroll
    for (int n = 0; n < 4; ++n) b[n] = *(const s16x8*)&Bs[(wn + n * 16 + fr) * 32 + fk];
#pragma unroll
    for (int m = 0; m < 4; ++m)
#pragma unroll
      for (int n = 0; n < 4; ++n)
        acc[m][n] = mfma_bf16(a[m], b[n], acc[m][n]);
    __syncthreads();
  }

  const long col0 = bcol + wn + fr;
  const long row0 = brow + wm + ((lane >> 4) << 2);
#pragma unroll
  for (int n = 0; n < 4; ++n) {
    long col = col0 + n * 16;
    if (!CBF16 && col >= Ntrue) continue;
    float bv = bias[col];
#pragma unroll
    for (int m = 0; m < 4; ++m) {
#pragma unroll
      for (int i = 0; i < 4; ++i) {
        float v = acc[m][n][i] + bv;
        if (RELU) v = fmaxf(v, 0.0f);
        long off = (row0 + m * 16 + i) * (long)Ntrue + col;
        if (CBF16) ((u16*)Cv)[off] = f2bf(v);
        else ((float*)Cv)[off] = v;
      }
    }
  }
}

// ---------------- launch ----------------
extern "C" void kernel_launch(void* const* d_in, const int* in_sizes, int n_in,
                              void* d_out, int out_size, void* d_ws, size_t ws_size,
                              hipStream_t stream) {
  const float* x  = (const float*)d_in[0];
  const float* w1 = (const float*)d_in[1];
  const float* s1 = (const float*)d_in[2];
  const float* b1 = (const float*)d_in[3];
  const float* w2 = (const float*)d_in[4];
  const float* s2 = (const float*)d_in[5];
  const float* b2 = (const float*)d_in[6];
  const float* w3 = (const float*)d_in[7];
  const float* s3 = (const float*)d_in[8];
  const float* b3 = (const float*)d_in[9];
  float* out = (float*)d_out;

  const int n1 = 4096 * 2048, n2 = 4096 * 4096, n3 = 1000 * 4096;

  char* ws = (char*)d_ws;
  u32*   meta = (u32*)ws;                  // 3 x 8 u32
  u32*   gh1  = (u32*)(ws + 0x1000);       // 3 x 1024
  u32*   gh2  = (u32*)(ws + 0x4000);       // 3 x 4096, ends 0x10000
  uint2* cand = (uint2*)(ws + 0x10000);    // 3 x 65536 x 8B, ends 0x190000
  u16* Wb = (u16*)(ws + (2l  << 20));      // 32 MiB, reused per layer
  u16* H1 = (u16*)(ws + (34l << 20));      // 32 MiB
  u16* H2 = (u16*)(ws + (66l << 20));      // 32 MiB
  u16* Xb = (u16*)(ws + (66l << 20));      // 16 MiB, aliases H2 (dead before GEMM2 writes H2)

  // x -> bf16
  f32_to_bf16_k<<<1024, 256, 0, stream>>>((const float4*)x, (ushort4*)Xb, n1 / 4);

  // fused selection: hists + selects for all 3 layers
  hipMemsetAsync(ws, 0, 0x10000, stream);
  hist1_k<<<256, 1024, 0, stream>>>((const uint4*)s1, n1 / 4, (const uint4*)s2, n2 / 4,
                                    (const uint4*)s3, n3 / 4, gh1);
  select_k<1><<<3, 256, 0, stream>>>(gh1, meta, (u32)(n1 / 2), (u32)(n2 / 2), (u32)(n3 / 2));
  hist2_k<<<256, 1024, 0, stream>>>((const uint4*)s1, n1 / 4, (const uint4*)s2, n2 / 4,
                                    (const uint4*)s3, n3 / 4, gh2, meta);
  select_k<2><<<3, 256, 0, stream>>>(gh2, meta, 0, 0, 0);

  // Layer 1: (4096x2048) -> 4096, relu, bf16
  build_k<<<512, 256, 0, stream>>>((const float4*)w1, (const uint4*)s1, (ushort4*)Wb,
                                   n1 / 4, meta + 0, cand + 0);
  finalize_k<<<1, 1024, 0, stream>>>(Wb, w1, meta + 0, cand + 0);
  gemm256<<<dim3(16, 16), 512, 0, stream>>>(Xb, Wb, b1, H1, 4096, 2048);

  // Layer 2: 4096 -> 4096, relu, bf16
  build_k<<<512, 256, 0, stream>>>((const float4*)w2, (const uint4*)s2, (ushort4*)Wb,
                                   n2 / 4, meta + 8, cand + CANDCAP);
  finalize_k<<<1, 1024, 0, stream>>>(Wb, w2, meta + 8, cand + CANDCAP);
  gemm256<<<dim3(16, 16), 512, 0, stream>>>(H1, Wb, b2, H2, 4096, 4096);

  // Layer 3: 4096 -> 1000 (padded to 1024 rows), fp32 out
  build_k<<<512, 256, 0, stream>>>((const float4*)w3, (const uint4*)s3, (ushort4*)Wb,
                                   n3 / 4, meta + 16, cand + 2 * CANDCAP);
  finalize_k<<<1, 1024, 0, stream>>>(Wb, w3, meta + 16, cand + 2 * CANDCAP);
  hipMemsetAsync((char*)Wb + (size_t)1000 * 4096 * 2, 0, (size_t)24 * 4096 * 2, stream);
  gemm_bt<0, 0><<<dim3(8, 32), 256, 0, stream>>>(H2, Wb, b3, out, 1000, 4096);
}